// Round 8
// baseline (483.686 us; speedup 1.0000x reference)
//
#include <hip/hip_runtime.h>
#include <math.h>

#define NN   100000
#define NE   1600000
#define DIN  128
#define HID  256
#define NG   64
#define NCLS 10

// counting-sort CSR build parameters
#define NBLK 128          // edge-chunk blocks (NE/NBLK = 12500 exactly)
#define EPB  (NE / NBLK)
#define NBUK 512          // dst buckets
#define NPB  196          // nodes per bucket (512*196 = 100352 >= NN)

using bf16x8 = __attribute__((ext_vector_type(8))) short;
using f32x4  = __attribute__((ext_vector_type(4))) float;
using u32x2  = __attribute__((ext_vector_type(2))) unsigned int;

static __device__ __forceinline__ unsigned short f2bf(float f) {
    unsigned u = __float_as_uint(f);
    u += 0x7fff + ((u >> 16) & 1);   // round-to-nearest-even
    return (unsigned short)(u >> 16);
}
static __device__ __forceinline__ float bf2f(unsigned short h) {
    return __uint_as_float(((unsigned)h) << 16);
}

// ---------------- graph preprocessing: bucketed counting sort ----------------

__global__ __launch_bounds__(256) void k_hist(const int* __restrict__ dst,
                                              int* __restrict__ histg) {
    __shared__ int h[NBUK];
    const int t = threadIdx.x;
    for (int i = t; i < NBUK; i += 256) h[i] = 0;
    __syncthreads();
    const int e0 = blockIdx.x * EPB, e1 = e0 + EPB;
    for (int e = e0 + t; e < e1; e += 256)
        atomicAdd(&h[(unsigned)__builtin_nontemporal_load(&dst[e]) / NPB], 1);
    __syncthreads();
    for (int i = t; i < NBUK; i += 256)
        histg[i * NBLK + blockIdx.x] = h[i];
}

__global__ __launch_bounds__(1024) void k_scan64k(int* __restrict__ d) {
    __shared__ int ts[1024];
    const int t = threadIdx.x;
    const int base = t * 64;
    int s = 0;
    for (int i = 0; i < 64; ++i) s += d[base + i];
    ts[t] = s;
    __syncthreads();
    for (int off = 1; off < 1024; off <<= 1) {
        int u = (t >= off) ? ts[t - off] : 0;
        __syncthreads();
        ts[t] += u;
        __syncthreads();
    }
    int run = ts[t] - s;
    for (int i = 0; i < 64; ++i) {
        int v = d[base + i];
        d[base + i] = run;
        run += v;
    }
}

__global__ __launch_bounds__(256) void k_scatter(const int* __restrict__ src,
                                                 const int* __restrict__ dst,
                                                 const int* __restrict__ offg,
                                                 int2* __restrict__ pairs) {
    __shared__ int cur[NBUK];
    const int t = threadIdx.x;
    for (int i = t; i < NBUK; i += 256) cur[i] = offg[i * NBLK + blockIdx.x];
    __syncthreads();
    const int e0 = blockIdx.x * EPB, e1 = e0 + EPB;
    for (int e = e0 + t; e < e1; e += 256) {
        int d = __builtin_nontemporal_load(&dst[e]);
        int sv = __builtin_nontemporal_load(&src[e]);
        int b = (unsigned)d / NPB;
        int p = atomicAdd(&cur[b], 1);
        u32x2 pv; pv.x = (unsigned)sv; pv.y = (unsigned)d;
        __builtin_nontemporal_store(pv, (u32x2*)&pairs[p]);
    }
}

__global__ __launch_bounds__(256) void k_csr(const int2* __restrict__ pairs,
                                             const int* __restrict__ offg,
                                             int* __restrict__ csr,
                                             int* __restrict__ deg,
                                             float* __restrict__ dinv,
                                             int* __restrict__ offs) {
    __shared__ int cnt[NPB];
    __shared__ int loff[256];
    __shared__ int cur[NPB];
    const int b = blockIdx.x, t = threadIdx.x;
    const int s     = offg[b * NBLK];
    const int e_end = (b == NBUK - 1) ? NE : offg[(b + 1) * NBLK];
    const int nb0   = b * NPB;
    const int nnod  = min(NPB, NN - nb0);
    if (t < NPB) cnt[t] = 0;
    __syncthreads();
    for (int e = s + t; e < e_end; e += 256)
        atomicAdd(&cnt[pairs[e].y - nb0], 1);
    __syncthreads();
    int v = (t < NPB) ? cnt[t] : 0;
    loff[t] = v;
    __syncthreads();
    for (int off = 1; off < 256; off <<= 1) {
        int u = (t >= off) ? loff[t - off] : 0;
        __syncthreads();
        loff[t] += u;
        __syncthreads();
    }
    int myoff = loff[t] - v;
    __syncthreads();
    loff[t] = myoff;
    if (t < NPB) cur[t] = 0;
    __syncthreads();
    if (t < nnod) {
        int node = nb0 + t;
        int dg = cnt[t];
        deg[node]  = dg;
        dinv[node] = rsqrtf((float)(dg + 1));
        offs[node] = s + myoff;
    }
    for (int e = s + t; e < e_end; e += 256) {
        int2 pr = pairs[e];
        int li = pr.y - nb0;
        int p = atomicAdd(&cur[li], 1);
        csr[s + loff[li] + p] = pr.x;
    }
}

// countsf[g] = #nodes in graph g (batch sorted -> binary search)
__global__ void k_counts(const int* __restrict__ batch, float* __restrict__ countsf) {
    int g = threadIdx.x;
    if (g >= NG) return;
    int lo = 0, hi = NN;
    while (lo < hi) { int mid = (lo + hi) >> 1; if (batch[mid] < g) lo = mid + 1; else hi = mid; }
    int lb = lo;
    lo = 0; hi = NN;
    while (lo < hi) { int mid = (lo + hi) >> 1; if (batch[mid] <= g) lo = mid + 1; else hi = mid; }
    countsf[g] = (float)(lo - lb);
}

// ---------------- casts ----------------

__global__ void k_cast_scale_x(const float* __restrict__ x, const float* __restrict__ dinv,
                               unsigned short* __restrict__ xb, int n4) {
    int i = blockIdx.x * blockDim.x + threadIdx.x;
    if (i >= n4) return;
    float dv = dinv[i >> 5];
    const float4 v = *(const float4*)&x[i * 4];
    ushort4 o;
    o.x = f2bf(v.x * dv); o.y = f2bf(v.y * dv);
    o.z = f2bf(v.z * dv); o.w = f2bf(v.w * dv);
    u32x2 w = *(u32x2*)&o;
    __builtin_nontemporal_store(w, (u32x2*)&xb[i * 4]);
}

// both weight transposes in one launch: i < (DIN+HID)*HID
__global__ void k_cast_wt2(const float* __restrict__ W1, unsigned short* __restrict__ Wt1,
                           const float* __restrict__ W2, unsigned short* __restrict__ Wt2) {
    int i = blockIdx.x * blockDim.x + threadIdx.x;
    if (i < DIN * HID) {
        int k = i >> 8, nc = i & 255;
        Wt1[nc * DIN + k] = f2bf(W1[i]);
    } else if (i < (DIN + HID) * HID) {
        int j = i - DIN * HID;
        int k = j >> 8, nc = j & 255;
        Wt2[nc * HID + k] = f2bf(W2[j]);
    }
}

// ---------------- MFMA GEMM with fused epilogue ----------------
// MODE 1: out = bf16(dinv[row] * relu(acc + bias[col]))           (layer-1)
// MODE 2: fused pooling: pooled[batch[row]][col] += relu(acc+bias) (layer-2, no store)

template <int MODE>
__global__ __launch_bounds__(256) void k_gemm_mfma(const unsigned short* __restrict__ A,
                                                   const unsigned short* __restrict__ Wt,
                                                   const float* __restrict__ dinv,
                                                   const float* __restrict__ bias,
                                                   unsigned short* __restrict__ out,
                                                   const int* __restrict__ batch,
                                                   float* __restrict__ pooled,
                                                   int M, int K) {
    __shared__ unsigned short As[128 * 40];
    __shared__ unsigned short Bs[128 * 40];
    __shared__ float psum[4][128];
    const int t = threadIdx.x;
    const int lane = t & 63;
    const int wid = t >> 6;
    const int wr = wid >> 1, wc = wid & 1;
    const int bm = blockIdx.x * 128, bn = blockIdx.y * 128;
    const int lr = lane & 15;
    const int ko = (lane >> 4) << 3;

    f32x4 acc[4][4] = {};

    const int r = t >> 2;
    const int kq = (t & 3) << 3;

    if (MODE == 2) {
        for (int i = t; i < 4 * 128; i += 256) ((float*)psum)[i] = 0.f;
        // no barrier needed yet: psum not touched until after K-loop's syncthreads
    }

    for (int kk = 0; kk < K; kk += 32) {
#pragma unroll
        for (int h = 0; h < 128; h += 64) {
            int row = bm + r + h;
            int4 v = make_int4(0, 0, 0, 0);
            if (row < M) v = *(const int4*)&A[(size_t)row * K + kk + kq];
            *(int4*)&As[(r + h) * 40 + kq] = v;
        }
#pragma unroll
        for (int h = 0; h < 128; h += 64) {
            int nrow = bn + r + h;
            int4 v = *(const int4*)&Wt[(size_t)nrow * K + kk + kq];
            *(int4*)&Bs[(r + h) * 40 + kq] = v;
        }
        __syncthreads();
        bf16x8 af[4], bfr[4];
#pragma unroll
        for (int mf = 0; mf < 4; ++mf)
            af[mf] = *(const bf16x8*)&As[(wr * 64 + mf * 16 + lr) * 40 + ko];
#pragma unroll
        for (int nf = 0; nf < 4; ++nf)
            bfr[nf] = *(const bf16x8*)&Bs[(wc * 64 + nf * 16 + lr) * 40 + ko];
#pragma unroll
        for (int mf = 0; mf < 4; ++mf)
#pragma unroll
            for (int nf = 0; nf < 4; ++nf)
                acc[mf][nf] = __builtin_amdgcn_mfma_f32_16x16x32_bf16(af[mf], bfr[nf], acc[mf][nf], 0, 0, 0);
        __syncthreads();
    }

    if (MODE == 1) {
#pragma unroll
        for (int mf = 0; mf < 4; ++mf) {
#pragma unroll
            for (int b = 0; b < 4; ++b) {
                int row = bm + wr * 64 + mf * 16 + (lane >> 4) * 4 + b;
                if (row >= M) continue;
                float dv = dinv[row];
#pragma unroll
                for (int nf = 0; nf < 4; ++nf) {
                    int col = bn + wc * 64 + nf * 16 + lr;
                    float v = fmaxf(acc[mf][nf][b] + bias[col], 0.f);
                    __builtin_nontemporal_store(f2bf(dv * v), &out[(size_t)row * HID + col]);
                }
            }
        }
    } else {
        const int g0 = batch[bm];
#pragma unroll
        for (int mf = 0; mf < 4; ++mf) {
#pragma unroll
            for (int b = 0; b < 4; ++b) {
                int row = bm + wr * 64 + mf * 16 + (lane >> 4) * 4 + b;
                if (row >= M) continue;
                int gl = batch[row] - g0;
#pragma unroll
                for (int nf = 0; nf < 4; ++nf) {
                    int lcol = wc * 64 + nf * 16 + lr;
                    float v = fmaxf(acc[mf][nf][b] + bias[bn + lcol], 0.f);
                    if (v != 0.f) {
                        if (gl < 4) atomicAdd(&psum[gl][lcol], v);
                        else        atomicAdd(&pooled[(size_t)(g0 + gl) * HID + bn + lcol], v);
                    }
                }
            }
        }
        __syncthreads();
        for (int i = t; i < 4 * 128; i += 256) {
            int gl = i >> 7, lcol = i & 127;
            int g = g0 + gl;
            float v = psum[gl][lcol];
            if (g < NG && v != 0.f)
                atomicAdd(&pooled[(size_t)g * HID + bn + lcol], v);
        }
    }
}

// ---------------- aggregation, 256 channels, 8-deep MLP ----------------

__global__ __launch_bounds__(256) void k_agg256(const unsigned short* __restrict__ hs,
                                                const int* __restrict__ csr,
                                                const int* __restrict__ offs,
                                                const int* __restrict__ deg,
                                                const float* __restrict__ dinv,
                                                unsigned short* __restrict__ out, int n) {
    int wid = threadIdx.x >> 6, lane = threadIdx.x & 63;
    int node = blockIdx.x * 4 + wid;
    if (node >= n) return;
    int c = lane << 2;
    const ushort4 self = *(const ushort4*)&hs[(size_t)node * HID + c];
    float a0 = bf2f(self.x), a1 = bf2f(self.y), a2 = bf2f(self.z), a3 = bf2f(self.w);
    int s0 = offs[node], cnt = deg[node];
    for (int base = 0; base < cnt; base += 64) {
        int nb = min(64, cnt - base);
        int idx = (lane < nb) ? __builtin_nontemporal_load(&csr[s0 + base + lane]) : 0;
        int i = 0;
        for (; i + 8 <= nb; i += 8) {
            ushort4 v[8];
#pragma unroll
            for (int k = 0; k < 8; ++k) {
                int j = __shfl(idx, i + k);
                v[k] = *(const ushort4*)&hs[(size_t)j * HID + c];
            }
#pragma unroll
            for (int k = 0; k < 8; ++k) {
                a0 += bf2f(v[k].x); a1 += bf2f(v[k].y);
                a2 += bf2f(v[k].z); a3 += bf2f(v[k].w);
            }
        }
        for (; i + 4 <= nb; i += 4) {
            ushort4 v[4];
#pragma unroll
            for (int k = 0; k < 4; ++k) {
                int j = __shfl(idx, i + k);
                v[k] = *(const ushort4*)&hs[(size_t)j * HID + c];
            }
#pragma unroll
            for (int k = 0; k < 4; ++k) {
                a0 += bf2f(v[k].x); a1 += bf2f(v[k].y);
                a2 += bf2f(v[k].z); a3 += bf2f(v[k].w);
            }
        }
        for (; i < nb; ++i) {
            int j = __shfl(idx, i);
            const ushort4 v = *(const ushort4*)&hs[(size_t)j * HID + c];
            a0 += bf2f(v.x); a1 += bf2f(v.y); a2 += bf2f(v.z); a3 += bf2f(v.w);
        }
    }
    float dv = dinv[node];
    ushort4 r;
    r.x = f2bf(dv * a0); r.y = f2bf(dv * a1);
    r.z = f2bf(dv * a2); r.w = f2bf(dv * a3);
    u32x2 w = *(u32x2*)&r;
    __builtin_nontemporal_store(w, (u32x2*)&out[(size_t)node * HID + c]);
}

// ---------------- aggregation, 128 channels, 8-deep (4 per 32-lane half) ----------------

__global__ __launch_bounds__(256) void k_agg128(const unsigned short* __restrict__ xs,
                                                const int* __restrict__ csr,
                                                const int* __restrict__ offs,
                                                const int* __restrict__ deg,
                                                const float* __restrict__ dinv,
                                                unsigned short* __restrict__ out, int n) {
    int wid = threadIdx.x >> 6, lane = threadIdx.x & 63;
    int node = blockIdx.x * 4 + wid;
    if (node >= n) return;
    int half = lane >> 5, l32 = lane & 31;
    int c = l32 << 2;
    float a0 = 0.f, a1 = 0.f, a2 = 0.f, a3 = 0.f;
    if (half == 0) {
        const ushort4 s = *(const ushort4*)&xs[(size_t)node * DIN + c];
        a0 = bf2f(s.x); a1 = bf2f(s.y); a2 = bf2f(s.z); a3 = bf2f(s.w);
    }
    int s0 = offs[node], cnt = deg[node];
    for (int base = 0; base < cnt; base += 64) {
        int nb = min(64, cnt - base);
        int idx = (lane < nb) ? __builtin_nontemporal_load(&csr[s0 + base + lane]) : 0;
        int i = 0;
        for (; i + 8 <= nb; i += 8) {
            ushort4 v[4];
#pragma unroll
            for (int k = 0; k < 4; ++k) {
                int j = __shfl(idx, i + 2 * k + half);
                v[k] = *(const ushort4*)&xs[(size_t)j * DIN + c];
            }
#pragma unroll
            for (int k = 0; k < 4; ++k) {
                a0 += bf2f(v[k].x); a1 += bf2f(v[k].y);
                a2 += bf2f(v[k].z); a3 += bf2f(v[k].w);
            }
        }
        for (; i < nb; i += 2) {
            int e = i + half;
            int j = __shfl(idx, e < nb ? e : 0);
            if (e < nb) {
                const ushort4 v = *(const ushort4*)&xs[(size_t)j * DIN + c];
                a0 += bf2f(v.x); a1 += bf2f(v.y); a2 += bf2f(v.z); a3 += bf2f(v.w);
            }
        }
    }
    a0 += __shfl_xor(a0, 32);
    a1 += __shfl_xor(a1, 32);
    a2 += __shfl_xor(a2, 32);
    a3 += __shfl_xor(a3, 32);
    if (half == 0) {
        float dv = dinv[node];
        ushort4 r;
        r.x = f2bf(dv * a0); r.y = f2bf(dv * a1);
        r.z = f2bf(dv * a2); r.w = f2bf(dv * a3);
        u32x2 w = *(u32x2*)&r;
        __builtin_nontemporal_store(w, (u32x2*)&out[(size_t)node * DIN + c]);
    }
}

// ---------------- head MLP ----------------

__global__ __launch_bounds__(256) void k_mlp(const float* __restrict__ pooled,
                                             const float* __restrict__ countsf,
                                             const float* __restrict__ Wf1,
                                             const float* __restrict__ bf1,
                                             const float* __restrict__ Wf2,
                                             const float* __restrict__ bf2,
                                             float* __restrict__ out) {
    __shared__ float p[HID];
    __shared__ float z[HID];
    int g = blockIdx.x, t = threadIdx.x;
    float cnt = fmaxf(countsf[g], 1.0f);
    p[t] = pooled[g * HID + t] / cnt;
    __syncthreads();
    float accz = bf1[t];
    for (int k = 0; k < HID; ++k)
        accz = fmaf(p[k], Wf1[k * HID + t], accz);
    z[t] = fmaxf(accz, 0.f);
    __syncthreads();
    if (t < NCLS) {
        float o = bf2[t];
        for (int k = 0; k < HID; ++k)
            o = fmaf(z[k], Wf2[k * NCLS + t], o);
        float sp = fmaxf(o, 0.f) + log1pf(expf(-fabsf(o)));
        out[g * NCLS + t] = sp + 0.001f;
    }
}

// ---------------- launch ----------------

extern "C" void kernel_launch(void* const* d_in, const int* in_sizes, int n_in,
                              void* d_out, int out_size, void* d_ws, size_t ws_size,
                              hipStream_t stream) {
    const float* x     = (const float*)d_in[0];
    const int*   ei    = (const int*)d_in[1];
    const int*   batch = (const int*)d_in[2];
    const float* W1    = (const float*)d_in[3];
    const float* b1    = (const float*)d_in[4];
    const float* W2    = (const float*)d_in[5];
    const float* b2    = (const float*)d_in[6];
    const float* Wf1   = (const float*)d_in[7];
    const float* bf1   = (const float*)d_in[8];
    const float* Wf2   = (const float*)d_in[9];
    const float* bf2   = (const float*)d_in[10];
    float* out = (float*)d_out;

    const int* srcv = ei;
    const int* dstv = ei + NE;

    char* p = (char*)d_ws;
    auto take = [&](size_t bytes) -> char* {
        char* q = p; p += (bytes + 255) & ~(size_t)255; return q;
    };
    unsigned short* big0 = (unsigned short*)take((size_t)NN * HID * 2);
    unsigned short* big1 = (unsigned short*)take((size_t)NN * HID * 2);
    unsigned short* xs = big0;
    unsigned short* xa = big0 + (size_t)NN * DIN;
    unsigned short* hB = big1;
    unsigned short* rB = big0;
    int2* pairs = (int2*)big1;            // alias: dead before hB written
    unsigned short* wt1  = (unsigned short*)take((size_t)DIN * HID * 2);
    unsigned short* wt2  = (unsigned short*)take((size_t)HID * HID * 2);
    int*   histg   = (int*)take((size_t)NBUK * NBLK * 4);
    int*   deg     = (int*)take((size_t)NN * 4);
    int*   offs    = (int*)take((size_t)NN * 4);
    int*   csr     = (int*)take((size_t)NE * 4);
    float* dinv    = (float*)take((size_t)NN * 4);
    float* pooled  = (float*)take((size_t)NG * HID * 4);
    float* countsf = (float*)take((size_t)NG * 4);

    hipMemsetAsync(pooled, 0, (size_t)NG * HID * 4, stream);

    k_hist<<<NBLK, 256, 0, stream>>>(dstv, histg);
    k_scan64k<<<1, 1024, 0, stream>>>(histg);
    k_scatter<<<NBLK, 256, 0, stream>>>(srcv, dstv, histg, pairs);
    k_csr<<<NBUK, 256, 0, stream>>>(pairs, histg, csr, deg, dinv, offs);
    k_counts<<<1, 64, 0, stream>>>(batch, countsf);

    k_cast_scale_x<<<(NN * DIN / 4 + 255) / 256, 256, 0, stream>>>(x, dinv, xs, NN * DIN / 4);
    k_cast_wt2<<<((DIN + HID) * HID + 255) / 256, 256, 0, stream>>>(W1, wt1, W2, wt2);

    dim3 gg((NN + 127) / 128, HID / 128);
    // layer 1
    k_agg128<<<(NN + 3) / 4, 256, 0, stream>>>(xs, csr, offs, deg, dinv, xa, NN);
    k_gemm_mfma<1><<<gg, 256, 0, stream>>>(xa, wt1, dinv, b1, hB, batch, pooled, NN, DIN);
    // layer 2 (+ fused pooling)
    k_agg256<<<(NN + 3) / 4, 256, 0, stream>>>(hB, csr, offs, deg, dinv, rB, NN);
    k_gemm_mfma<2><<<gg, 256, 0, stream>>>(rB, wt2, dinv, b2, hB, batch, pooled, NN, HID);

    k_mlp<<<NG, 256, 0, stream>>>(pooled, countsf, Wf1, bf1, Wf2, bf2, out);
}

// Round 9
// 430.765 us; speedup vs baseline: 1.1229x; 1.1229x over previous
//
#include <hip/hip_runtime.h>
#include <math.h>

#define NN   100000
#define NE   1600000
#define DIN  128
#define HID  256
#define NG   64
#define NCLS 10

// counting-sort CSR build parameters
#define NBLK 128          // edge-chunk blocks (NE/NBLK = 12500 exactly)
#define EPB  (NE / NBLK)
#define NBUK 512          // dst buckets
#define NPB  196          // nodes per bucket (512*196 = 100352 >= NN)

using bf16x8 = __attribute__((ext_vector_type(8))) short;
using f32x4  = __attribute__((ext_vector_type(4))) float;
using u32x2  = __attribute__((ext_vector_type(2))) unsigned int;

static __device__ __forceinline__ unsigned short f2bf(float f) {
    unsigned u = __float_as_uint(f);
    u += 0x7fff + ((u >> 16) & 1);   // round-to-nearest-even
    return (unsigned short)(u >> 16);
}
static __device__ __forceinline__ float bf2f(unsigned short h) {
    return __uint_as_float(((unsigned)h) << 16);
}

// ---------------- graph preprocessing: bucketed counting sort ----------------

__global__ __launch_bounds__(256) void k_hist(const int* __restrict__ dst,
                                              int* __restrict__ histg) {
    __shared__ int h[NBUK];
    const int t = threadIdx.x;
    for (int i = t; i < NBUK; i += 256) h[i] = 0;
    __syncthreads();
    const int e0 = blockIdx.x * EPB, e1 = e0 + EPB;
    for (int e = e0 + t; e < e1; e += 256)
        atomicAdd(&h[(unsigned)__builtin_nontemporal_load(&dst[e]) / NPB], 1);
    __syncthreads();
    for (int i = t; i < NBUK; i += 256)
        histg[i * NBLK + blockIdx.x] = h[i];
}

__global__ __launch_bounds__(1024) void k_scan64k(int* __restrict__ d) {
    __shared__ int ts[1024];
    const int t = threadIdx.x;
    const int base = t * 64;
    int s = 0;
    for (int i = 0; i < 64; ++i) s += d[base + i];
    ts[t] = s;
    __syncthreads();
    for (int off = 1; off < 1024; off <<= 1) {
        int u = (t >= off) ? ts[t - off] : 0;
        __syncthreads();
        ts[t] += u;
        __syncthreads();
    }
    int run = ts[t] - s;
    for (int i = 0; i < 64; ++i) {
        int v = d[base + i];
        d[base + i] = run;
        run += v;
    }
}

__global__ __launch_bounds__(256) void k_scatter(const int* __restrict__ src,
                                                 const int* __restrict__ dst,
                                                 const int* __restrict__ offg,
                                                 int2* __restrict__ pairs) {
    __shared__ int cur[NBUK];
    const int t = threadIdx.x;
    for (int i = t; i < NBUK; i += 256) cur[i] = offg[i * NBLK + blockIdx.x];
    __syncthreads();
    const int e0 = blockIdx.x * EPB, e1 = e0 + EPB;
    for (int e = e0 + t; e < e1; e += 256) {
        int d = __builtin_nontemporal_load(&dst[e]);
        int sv = __builtin_nontemporal_load(&src[e]);
        int b = (unsigned)d / NPB;
        int p = atomicAdd(&cur[b], 1);
        u32x2 pv; pv.x = (unsigned)sv; pv.y = (unsigned)d;
        __builtin_nontemporal_store(pv, (u32x2*)&pairs[p]);
    }
}

__global__ __launch_bounds__(256) void k_csr(const int2* __restrict__ pairs,
                                             const int* __restrict__ offg,
                                             int* __restrict__ csr,
                                             int* __restrict__ deg,
                                             float* __restrict__ dinv,
                                             int* __restrict__ offs) {
    __shared__ int cnt[NPB];
    __shared__ int loff[256];
    __shared__ int cur[NPB];
    const int b = blockIdx.x, t = threadIdx.x;
    const int s     = offg[b * NBLK];
    const int e_end = (b == NBUK - 1) ? NE : offg[(b + 1) * NBLK];
    const int nb0   = b * NPB;
    const int nnod  = min(NPB, NN - nb0);
    if (t < NPB) cnt[t] = 0;
    __syncthreads();
    for (int e = s + t; e < e_end; e += 256)
        atomicAdd(&cnt[pairs[e].y - nb0], 1);
    __syncthreads();
    int v = (t < NPB) ? cnt[t] : 0;
    loff[t] = v;
    __syncthreads();
    for (int off = 1; off < 256; off <<= 1) {
        int u = (t >= off) ? loff[t - off] : 0;
        __syncthreads();
        loff[t] += u;
        __syncthreads();
    }
    int myoff = loff[t] - v;
    __syncthreads();
    loff[t] = myoff;
    if (t < NPB) cur[t] = 0;
    __syncthreads();
    if (t < nnod) {
        int node = nb0 + t;
        int dg = cnt[t];
        deg[node]  = dg;
        dinv[node] = rsqrtf((float)(dg + 1));
        offs[node] = s + myoff;
    }
    for (int e = s + t; e < e_end; e += 256) {
        int2 pr = pairs[e];
        int li = pr.y - nb0;
        int p = atomicAdd(&cur[li], 1);
        csr[s + loff[li] + p] = pr.x;
    }
}

// countsf[g] = #nodes in graph g (batch sorted -> binary search)
__global__ void k_counts(const int* __restrict__ batch, float* __restrict__ countsf) {
    int g = threadIdx.x;
    if (g >= NG) return;
    int lo = 0, hi = NN;
    while (lo < hi) { int mid = (lo + hi) >> 1; if (batch[mid] < g) lo = mid + 1; else hi = mid; }
    int lb = lo;
    lo = 0; hi = NN;
    while (lo < hi) { int mid = (lo + hi) >> 1; if (batch[mid] <= g) lo = mid + 1; else hi = mid; }
    countsf[g] = (float)(lo - lb);
}

// ---------------- casts ----------------

__global__ void k_cast_scale_x(const float* __restrict__ x, const float* __restrict__ dinv,
                               unsigned short* __restrict__ xb, int n4) {
    int i = blockIdx.x * blockDim.x + threadIdx.x;
    if (i >= n4) return;
    float dv = dinv[i >> 5];
    const float4 v = *(const float4*)&x[i * 4];
    ushort4 o;
    o.x = f2bf(v.x * dv); o.y = f2bf(v.y * dv);
    o.z = f2bf(v.z * dv); o.w = f2bf(v.w * dv);
    *(ushort4*)&xb[i * 4] = o;
}

// both weight transposes in one launch
__global__ void k_cast_wt2(const float* __restrict__ W1, unsigned short* __restrict__ Wt1,
                           const float* __restrict__ W2, unsigned short* __restrict__ Wt2) {
    int i = blockIdx.x * blockDim.x + threadIdx.x;
    if (i < DIN * HID) {
        int k = i >> 8, nc = i & 255;
        Wt1[nc * DIN + k] = f2bf(W1[i]);
    } else if (i < (DIN + HID) * HID) {
        int j = i - DIN * HID;
        int k = j >> 8, nc = j & 255;
        Wt2[nc * HID + k] = f2bf(W2[j]);
    }
}

// ---------------- MFMA GEMM with fused epilogue ----------------
// MODE 1: out = bf16(dinv[row] * relu(acc + bias[col]))            (layer-1)
// MODE 2: fused pooling via register run-length segment sum (batch sorted)

template <int MODE>
__global__ __launch_bounds__(256) void k_gemm_mfma(const unsigned short* __restrict__ A,
                                                   const unsigned short* __restrict__ Wt,
                                                   const float* __restrict__ dinv,
                                                   const float* __restrict__ bias,
                                                   unsigned short* __restrict__ out,
                                                   const int* __restrict__ batch,
                                                   float* __restrict__ pooled,
                                                   int M, int K) {
    __shared__ unsigned short As[128 * 40];
    __shared__ unsigned short Bs[128 * 40];
    __shared__ float psum[4][128];
    __shared__ int gloc[128];
    const int t = threadIdx.x;
    const int lane = t & 63;
    const int wid = t >> 6;
    const int wr = wid >> 1, wc = wid & 1;
    const int bm = blockIdx.x * 128, bn = blockIdx.y * 128;
    const int lr = lane & 15;
    const int ko = (lane >> 4) << 3;

    f32x4 acc[4][4] = {};

    const int r = t >> 2;
    const int kq = (t & 3) << 3;

    int g0 = 0;
    if (MODE == 2) {
        g0 = batch[bm];
        for (int i = t; i < 4 * 128; i += 256) ((float*)psum)[i] = 0.f;
        if (t < 128) gloc[t] = (bm + t < M) ? (batch[bm + t] - g0) : 0;
        // first K-loop __syncthreads() covers these before any use
    }

    for (int kk = 0; kk < K; kk += 32) {
#pragma unroll
        for (int h = 0; h < 128; h += 64) {
            int row = bm + r + h;
            int4 v = make_int4(0, 0, 0, 0);
            if (row < M) v = *(const int4*)&A[(size_t)row * K + kk + kq];
            *(int4*)&As[(r + h) * 40 + kq] = v;
        }
#pragma unroll
        for (int h = 0; h < 128; h += 64) {
            int nrow = bn + r + h;
            int4 v = *(const int4*)&Wt[(size_t)nrow * K + kk + kq];
            *(int4*)&Bs[(r + h) * 40 + kq] = v;
        }
        __syncthreads();
        bf16x8 af[4], bfr[4];
#pragma unroll
        for (int mf = 0; mf < 4; ++mf)
            af[mf] = *(const bf16x8*)&As[(wr * 64 + mf * 16 + lr) * 40 + ko];
#pragma unroll
        for (int nf = 0; nf < 4; ++nf)
            bfr[nf] = *(const bf16x8*)&Bs[(wc * 64 + nf * 16 + lr) * 40 + ko];
#pragma unroll
        for (int mf = 0; mf < 4; ++mf)
#pragma unroll
            for (int nf = 0; nf < 4; ++nf)
                acc[mf][nf] = __builtin_amdgcn_mfma_f32_16x16x32_bf16(af[mf], bfr[nf], acc[mf][nf], 0, 0, 0);
        __syncthreads();
    }

    if (MODE == 1) {
#pragma unroll
        for (int mf = 0; mf < 4; ++mf) {
#pragma unroll
            for (int b = 0; b < 4; ++b) {
                int row = bm + wr * 64 + mf * 16 + (lane >> 4) * 4 + b;
                if (row >= M) continue;
                float dv = dinv[row];
#pragma unroll
                for (int nf = 0; nf < 4; ++nf) {
                    int col = bn + wc * 64 + nf * 16 + lr;
                    float v = fmaxf(acc[mf][nf][b] + bias[col], 0.f);
                    out[(size_t)row * HID + col] = f2bf(dv * v);
                }
            }
        }
    } else {
        const int q4 = (lane >> 4) << 2;
#pragma unroll
        for (int nf = 0; nf < 4; ++nf) {
            const int lcol = wc * 64 + nf * 16 + lr;
            const float bb = bias[bn + lcol];
            float run = 0.f; int gcur = 0;
#pragma unroll
            for (int mf = 0; mf < 4; ++mf) {
#pragma unroll
                for (int b = 0; b < 4; ++b) {
                    int lrow = wr * 64 + mf * 16 + q4 + b;
                    if (bm + lrow < M) {
                        int gl = gloc[lrow];
                        float v = fmaxf(acc[mf][nf][b] + bb, 0.f);
                        if (gl != gcur) {
                            if (run != 0.f) {
                                if (gcur < 4) atomicAdd(&psum[gcur][lcol], run);
                                else atomicAdd(&pooled[(size_t)(g0 + gcur) * HID + bn + lcol], run);
                            }
                            run = 0.f; gcur = gl;
                        }
                        run += v;
                    }
                }
            }
            if (run != 0.f) {
                if (gcur < 4) atomicAdd(&psum[gcur][lcol], run);
                else atomicAdd(&pooled[(size_t)(g0 + gcur) * HID + bn + lcol], run);
            }
        }
        __syncthreads();
        for (int i = t; i < 4 * 128; i += 256) {
            int gl = i >> 7, lcol = i & 127;
            int g = g0 + gl;
            float v = psum[gl][lcol];
            if (g < NG && v != 0.f)
                atomicAdd(&pooled[(size_t)g * HID + bn + lcol], v);
        }
    }
}

// ---------------- aggregation, 256 channels, 8-deep MLP ----------------

__global__ __launch_bounds__(256) void k_agg256(const unsigned short* __restrict__ hs,
                                                const int* __restrict__ csr,
                                                const int* __restrict__ offs,
                                                const int* __restrict__ deg,
                                                const float* __restrict__ dinv,
                                                unsigned short* __restrict__ out, int n) {
    int wid = threadIdx.x >> 6, lane = threadIdx.x & 63;
    int node = blockIdx.x * 4 + wid;
    if (node >= n) return;
    int c = lane << 2;
    const ushort4 self = *(const ushort4*)&hs[(size_t)node * HID + c];
    float a0 = bf2f(self.x), a1 = bf2f(self.y), a2 = bf2f(self.z), a3 = bf2f(self.w);
    int s0 = offs[node], cnt = deg[node];
    for (int base = 0; base < cnt; base += 64) {
        int nb = min(64, cnt - base);
        int idx = (lane < nb) ? __builtin_nontemporal_load(&csr[s0 + base + lane]) : 0;
        int i = 0;
        for (; i + 8 <= nb; i += 8) {
            ushort4 v[8];
#pragma unroll
            for (int k = 0; k < 8; ++k) {
                int j = __shfl(idx, i + k);
                v[k] = *(const ushort4*)&hs[(size_t)j * HID + c];
            }
#pragma unroll
            for (int k = 0; k < 8; ++k) {
                a0 += bf2f(v[k].x); a1 += bf2f(v[k].y);
                a2 += bf2f(v[k].z); a3 += bf2f(v[k].w);
            }
        }
        for (; i + 4 <= nb; i += 4) {
            ushort4 v[4];
#pragma unroll
            for (int k = 0; k < 4; ++k) {
                int j = __shfl(idx, i + k);
                v[k] = *(const ushort4*)&hs[(size_t)j * HID + c];
            }
#pragma unroll
            for (int k = 0; k < 4; ++k) {
                a0 += bf2f(v[k].x); a1 += bf2f(v[k].y);
                a2 += bf2f(v[k].z); a3 += bf2f(v[k].w);
            }
        }
        for (; i < nb; ++i) {
            int j = __shfl(idx, i);
            const ushort4 v = *(const ushort4*)&hs[(size_t)j * HID + c];
            a0 += bf2f(v.x); a1 += bf2f(v.y); a2 += bf2f(v.z); a3 += bf2f(v.w);
        }
    }
    float dv = dinv[node];
    ushort4 r;
    r.x = f2bf(dv * a0); r.y = f2bf(dv * a1);
    r.z = f2bf(dv * a2); r.w = f2bf(dv * a3);
    *(ushort4*)&out[(size_t)node * HID + c] = r;
}

// ---------------- aggregation, 128 channels, 8-deep (4 per 32-lane half) ----------------

__global__ __launch_bounds__(256) void k_agg128(const unsigned short* __restrict__ xs,
                                                const int* __restrict__ csr,
                                                const int* __restrict__ offs,
                                                const int* __restrict__ deg,
                                                const float* __restrict__ dinv,
                                                unsigned short* __restrict__ out, int n) {
    int wid = threadIdx.x >> 6, lane = threadIdx.x & 63;
    int node = blockIdx.x * 4 + wid;
    if (node >= n) return;
    int half = lane >> 5, l32 = lane & 31;
    int c = l32 << 2;
    float a0 = 0.f, a1 = 0.f, a2 = 0.f, a3 = 0.f;
    if (half == 0) {
        const ushort4 s = *(const ushort4*)&xs[(size_t)node * DIN + c];
        a0 = bf2f(s.x); a1 = bf2f(s.y); a2 = bf2f(s.z); a3 = bf2f(s.w);
    }
    int s0 = offs[node], cnt = deg[node];
    for (int base = 0; base < cnt; base += 64) {
        int nb = min(64, cnt - base);
        int idx = (lane < nb) ? __builtin_nontemporal_load(&csr[s0 + base + lane]) : 0;
        int i = 0;
        for (; i + 8 <= nb; i += 8) {
            ushort4 v[4];
#pragma unroll
            for (int k = 0; k < 4; ++k) {
                int j = __shfl(idx, i + 2 * k + half);
                v[k] = *(const ushort4*)&xs[(size_t)j * DIN + c];
            }
#pragma unroll
            for (int k = 0; k < 4; ++k) {
                a0 += bf2f(v[k].x); a1 += bf2f(v[k].y);
                a2 += bf2f(v[k].z); a3 += bf2f(v[k].w);
            }
        }
        for (; i < nb; i += 2) {
            int e = i + half;
            int j = __shfl(idx, e < nb ? e : 0);
            if (e < nb) {
                const ushort4 v = *(const ushort4*)&xs[(size_t)j * DIN + c];
                a0 += bf2f(v.x); a1 += bf2f(v.y); a2 += bf2f(v.z); a3 += bf2f(v.w);
            }
        }
    }
    a0 += __shfl_xor(a0, 32);
    a1 += __shfl_xor(a1, 32);
    a2 += __shfl_xor(a2, 32);
    a3 += __shfl_xor(a3, 32);
    if (half == 0) {
        float dv = dinv[node];
        ushort4 r;
        r.x = f2bf(dv * a0); r.y = f2bf(dv * a1);
        r.z = f2bf(dv * a2); r.w = f2bf(dv * a3);
        *(ushort4*)&out[(size_t)node * DIN + c] = r;
    }
}

// ---------------- head MLP ----------------

__global__ __launch_bounds__(256) void k_mlp(const float* __restrict__ pooled,
                                             const float* __restrict__ countsf,
                                             const float* __restrict__ Wf1,
                                             const float* __restrict__ bf1,
                                             const float* __restrict__ Wf2,
                                             const float* __restrict__ bf2,
                                             float* __restrict__ out) {
    __shared__ float p[HID];
    __shared__ float z[HID];
    int g = blockIdx.x, t = threadIdx.x;
    float cnt = fmaxf(countsf[g], 1.0f);
    p[t] = pooled[g * HID + t] / cnt;
    __syncthreads();
    float accz = bf1[t];
    for (int k = 0; k < HID; ++k)
        accz = fmaf(p[k], Wf1[k * HID + t], accz);
    z[t] = fmaxf(accz, 0.f);
    __syncthreads();
    if (t < NCLS) {
        float o = bf2[t];
        for (int k = 0; k < HID; ++k)
            o = fmaf(z[k], Wf2[k * NCLS + t], o);
        float sp = fmaxf(o, 0.f) + log1pf(expf(-fabsf(o)));
        out[g * NCLS + t] = sp + 0.001f;
    }
}

// ---------------- launch ----------------

extern "C" void kernel_launch(void* const* d_in, const int* in_sizes, int n_in,
                              void* d_out, int out_size, void* d_ws, size_t ws_size,
                              hipStream_t stream) {
    const float* x     = (const float*)d_in[0];
    const int*   ei    = (const int*)d_in[1];
    const int*   batch = (const int*)d_in[2];
    const float* W1    = (const float*)d_in[3];
    const float* b1    = (const float*)d_in[4];
    const float* W2    = (const float*)d_in[5];
    const float* b2    = (const float*)d_in[6];
    const float* Wf1   = (const float*)d_in[7];
    const float* bf1   = (const float*)d_in[8];
    const float* Wf2   = (const float*)d_in[9];
    const float* bf2   = (const float*)d_in[10];
    float* out = (float*)d_out;

    const int* srcv = ei;
    const int* dstv = ei + NE;

    char* p = (char*)d_ws;
    auto take = [&](size_t bytes) -> char* {
        char* q = p; p += (bytes + 255) & ~(size_t)255; return q;
    };
    unsigned short* big0 = (unsigned short*)take((size_t)NN * HID * 2);
    unsigned short* big1 = (unsigned short*)take((size_t)NN * HID * 2);
    unsigned short* xs = big0;
    unsigned short* xa = big0 + (size_t)NN * DIN;
    unsigned short* hB = big1;
    unsigned short* rB = big0;
    int2* pairs = (int2*)big1;            // alias: dead before hB written
    unsigned short* wt1  = (unsigned short*)take((size_t)DIN * HID * 2);
    unsigned short* wt2  = (unsigned short*)take((size_t)HID * HID * 2);
    int*   histg   = (int*)take((size_t)NBUK * NBLK * 4);
    int*   deg     = (int*)take((size_t)NN * 4);
    int*   offs    = (int*)take((size_t)NN * 4);
    int*   csr     = (int*)take((size_t)NE * 4);
    float* dinv    = (float*)take((size_t)NN * 4);
    float* pooled  = (float*)take((size_t)NG * HID * 4);
    float* countsf = (float*)take((size_t)NG * 4);

    hipMemsetAsync(pooled, 0, (size_t)NG * HID * 4, stream);

    k_hist<<<NBLK, 256, 0, stream>>>(dstv, histg);
    k_scan64k<<<1, 1024, 0, stream>>>(histg);
    k_scatter<<<NBLK, 256, 0, stream>>>(srcv, dstv, histg, pairs);
    k_csr<<<NBUK, 256, 0, stream>>>(pairs, histg, csr, deg, dinv, offs);
    k_counts<<<1, 64, 0, stream>>>(batch, countsf);

    k_cast_scale_x<<<(NN * DIN / 4 + 255) / 256, 256, 0, stream>>>(x, dinv, xs, NN * DIN / 4);
    k_cast_wt2<<<((DIN + HID) * HID + 255) / 256, 256, 0, stream>>>(W1, wt1, W2, wt2);

    dim3 gg((NN + 127) / 128, HID / 128);
    // layer 1
    k_agg128<<<(NN + 3) / 4, 256, 0, stream>>>(xs, csr, offs, deg, dinv, xa, NN);
    k_gemm_mfma<1><<<gg, 256, 0, stream>>>(xa, wt1, dinv, b1, hB, batch, pooled, NN, DIN);
    // layer 2 (+ fused pooling)
    k_agg256<<<(NN + 3) / 4, 256, 0, stream>>>(hB, csr, offs, deg, dinv, rB, NN);
    k_gemm_mfma<2><<<gg, 256, 0, stream>>>(rB, wt2, dinv, b2, hB, batch, pooled, NN, HID);

    k_mlp<<<NG, 256, 0, stream>>>(pooled, countsf, Wf1, bf1, Wf2, bf2, out);
}

// Round 10
// 381.830 us; speedup vs baseline: 1.2668x; 1.1282x over previous
//
#include <hip/hip_runtime.h>
#include <math.h>

#define NN   100000
#define NE   1600000
#define DIN  128
#define HID  256
#define NG   64
#define NCLS 10

// counting-sort CSR build parameters
#define NBLK 128          // edge-chunk blocks (NE/NBLK = 12500 exactly)
#define EPB  (NE / NBLK)
#define NBUK 512          // dst buckets
#define NPB  196          // nodes per bucket (512*196 = 100352 >= NN)

using bf16x8 = __attribute__((ext_vector_type(8))) short;
using f32x4  = __attribute__((ext_vector_type(4))) float;
using f32x2  = __attribute__((ext_vector_type(2))) float;
using u32x2  = __attribute__((ext_vector_type(2))) unsigned int;

static __device__ __forceinline__ unsigned short f2bf(float f) {
    unsigned u = __float_as_uint(f);
    u += 0x7fff + ((u >> 16) & 1);   // round-to-nearest-even
    return (unsigned short)(u >> 16);
}
static __device__ __forceinline__ float bf2f(unsigned short h) {
    return __uint_as_float(((unsigned)h) << 16);
}

// ---- OCP fp8 e4m3 helpers ----
// encode: RNE, saturate to 448 (values are >=0 post-relu; sign kept for generality)
static __device__ __forceinline__ unsigned char f32_to_fp8(float f) {
    float a = fminf(fabsf(f), 448.f);
    unsigned bits = __float_as_uint(a * 0x1p-120f);
    bits += 0x7ffff + ((bits >> 20) & 1);
    unsigned e4 = (bits >> 20) & 0x7f;
    return (unsigned char)(e4 | (f < 0.f ? 0x80u : 0u));
}
#if __has_builtin(__builtin_amdgcn_cvt_pk_f32_fp8)
#define HAVE_CVT_FP8 1
#endif
// decode 4 packed fp8 (little-endian byte order = channel order)
static __device__ __forceinline__ void fp8x4_to_f32(unsigned u, float* f) {
#ifdef HAVE_CVT_FP8
    f32x2 lo = __builtin_amdgcn_cvt_pk_f32_fp8((int)u, false);
    f32x2 hi = __builtin_amdgcn_cvt_pk_f32_fp8((int)u, true);
    f[0] = lo[0]; f[1] = lo[1]; f[2] = hi[0]; f[3] = hi[1];
#else
#pragma unroll
    for (int k = 0; k < 4; ++k) {
        unsigned b = (u >> (8 * k)) & 0xffu;
        unsigned bits = ((b & 0x80u) << 24) | ((b & 0x7fu) << 20);
        f[k] = __uint_as_float(bits) * 0x1p+120f;
    }
#endif
}

// ---------------- graph preprocessing: bucketed counting sort ----------------

__global__ __launch_bounds__(256) void k_hist(const int* __restrict__ dst,
                                              int* __restrict__ histg) {
    __shared__ int h[NBUK];
    const int t = threadIdx.x;
    for (int i = t; i < NBUK; i += 256) h[i] = 0;
    __syncthreads();
    const int e0 = blockIdx.x * EPB, e1 = e0 + EPB;
    for (int e = e0 + t; e < e1; e += 256)
        atomicAdd(&h[(unsigned)__builtin_nontemporal_load(&dst[e]) / NPB], 1);
    __syncthreads();
    for (int i = t; i < NBUK; i += 256)
        histg[i * NBLK + blockIdx.x] = h[i];
}

__global__ __launch_bounds__(1024) void k_scan64k(int* __restrict__ d) {
    __shared__ int ts[1024];
    const int t = threadIdx.x;
    const int base = t * 64;
    int s = 0;
    for (int i = 0; i < 64; ++i) s += d[base + i];
    ts[t] = s;
    __syncthreads();
    for (int off = 1; off < 1024; off <<= 1) {
        int u = (t >= off) ? ts[t - off] : 0;
        __syncthreads();
        ts[t] += u;
        __syncthreads();
    }
    int run = ts[t] - s;
    for (int i = 0; i < 64; ++i) {
        int v = d[base + i];
        d[base + i] = run;
        run += v;
    }
}

__global__ __launch_bounds__(256) void k_scatter(const int* __restrict__ src,
                                                 const int* __restrict__ dst,
                                                 const int* __restrict__ offg,
                                                 int2* __restrict__ pairs) {
    __shared__ int cur[NBUK];
    const int t = threadIdx.x;
    for (int i = t; i < NBUK; i += 256) cur[i] = offg[i * NBLK + blockIdx.x];
    __syncthreads();
    const int e0 = blockIdx.x * EPB, e1 = e0 + EPB;
    for (int e = e0 + t; e < e1; e += 256) {
        int d = __builtin_nontemporal_load(&dst[e]);
        int sv = __builtin_nontemporal_load(&src[e]);
        int b = (unsigned)d / NPB;
        int p = atomicAdd(&cur[b], 1);
        u32x2 pv; pv.x = (unsigned)sv; pv.y = (unsigned)d;
        __builtin_nontemporal_store(pv, (u32x2*)&pairs[p]);
    }
}

__global__ __launch_bounds__(256) void k_csr(const int2* __restrict__ pairs,
                                             const int* __restrict__ offg,
                                             int* __restrict__ csr,
                                             int* __restrict__ deg,
                                             float* __restrict__ dinv,
                                             int* __restrict__ offs) {
    __shared__ int cnt[NPB];
    __shared__ int loff[256];
    __shared__ int cur[NPB];
    const int b = blockIdx.x, t = threadIdx.x;
    const int s     = offg[b * NBLK];
    const int e_end = (b == NBUK - 1) ? NE : offg[(b + 1) * NBLK];
    const int nb0   = b * NPB;
    const int nnod  = min(NPB, NN - nb0);
    if (t < NPB) cnt[t] = 0;
    __syncthreads();
    for (int e = s + t; e < e_end; e += 256)
        atomicAdd(&cnt[pairs[e].y - nb0], 1);
    __syncthreads();
    int v = (t < NPB) ? cnt[t] : 0;
    loff[t] = v;
    __syncthreads();
    for (int off = 1; off < 256; off <<= 1) {
        int u = (t >= off) ? loff[t - off] : 0;
        __syncthreads();
        loff[t] += u;
        __syncthreads();
    }
    int myoff = loff[t] - v;
    __syncthreads();
    loff[t] = myoff;
    if (t < NPB) cur[t] = 0;
    __syncthreads();
    if (t < nnod) {
        int node = nb0 + t;
        int dg = cnt[t];
        deg[node]  = dg;
        dinv[node] = rsqrtf((float)(dg + 1));
        offs[node] = s + myoff;
    }
    for (int e = s + t; e < e_end; e += 256) {
        int2 pr = pairs[e];
        int li = pr.y - nb0;
        int p = atomicAdd(&cur[li], 1);
        csr[s + loff[li] + p] = pr.x;
    }
}

// countsf[g] = #nodes in graph g (batch sorted -> binary search)
__global__ void k_counts(const int* __restrict__ batch, float* __restrict__ countsf) {
    int g = threadIdx.x;
    if (g >= NG) return;
    int lo = 0, hi = NN;
    while (lo < hi) { int mid = (lo + hi) >> 1; if (batch[mid] < g) lo = mid + 1; else hi = mid; }
    int lb = lo;
    lo = 0; hi = NN;
    while (lo < hi) { int mid = (lo + hi) >> 1; if (batch[mid] <= g) lo = mid + 1; else hi = mid; }
    countsf[g] = (float)(lo - lb);
}

// ---------------- casts ----------------

__global__ void k_cast_scale_x(const float* __restrict__ x, const float* __restrict__ dinv,
                               unsigned short* __restrict__ xb, int n4) {
    int i = blockIdx.x * blockDim.x + threadIdx.x;
    if (i >= n4) return;
    float dv = dinv[i >> 5];
    const float4 v = *(const float4*)&x[i * 4];
    ushort4 o;
    o.x = f2bf(v.x * dv); o.y = f2bf(v.y * dv);
    o.z = f2bf(v.z * dv); o.w = f2bf(v.w * dv);
    *(ushort4*)&xb[i * 4] = o;
}

// both weight transposes in one launch
__global__ void k_cast_wt2(const float* __restrict__ W1, unsigned short* __restrict__ Wt1,
                           const float* __restrict__ W2, unsigned short* __restrict__ Wt2) {
    int i = blockIdx.x * blockDim.x + threadIdx.x;
    if (i < DIN * HID) {
        int k = i >> 8, nc = i & 255;
        Wt1[nc * DIN + k] = f2bf(W1[i]);
    } else if (i < (DIN + HID) * HID) {
        int j = i - DIN * HID;
        int k = j >> 8, nc = j & 255;
        Wt2[nc * HID + k] = f2bf(W2[j]);
    }
}

// ---------------- MFMA GEMM with fused epilogue ----------------
// MODE 1: out_fp8 = e4m3(dinv[row] * relu(acc + bias[col]))        (layer-1)
// MODE 2: fused pooling via register run-length segment sum (batch sorted)

template <int MODE>
__global__ __launch_bounds__(256) void k_gemm_mfma(const unsigned short* __restrict__ A,
                                                   const unsigned short* __restrict__ Wt,
                                                   const float* __restrict__ dinv,
                                                   const float* __restrict__ bias,
                                                   void* __restrict__ outp,
                                                   const int* __restrict__ batch,
                                                   float* __restrict__ pooled,
                                                   int M, int K) {
    __shared__ unsigned short As[128 * 40];
    __shared__ unsigned short Bs[128 * 40];
    __shared__ float psum[4][128];
    __shared__ int gloc[128];
    const int t = threadIdx.x;
    const int lane = t & 63;
    const int wid = t >> 6;
    const int wr = wid >> 1, wc = wid & 1;
    const int bm = blockIdx.x * 128, bn = blockIdx.y * 128;
    const int lr = lane & 15;
    const int ko = (lane >> 4) << 3;

    f32x4 acc[4][4] = {};

    const int r = t >> 2;
    const int kq = (t & 3) << 3;

    int g0 = 0;
    if (MODE == 2) {
        g0 = batch[bm];
        for (int i = t; i < 4 * 128; i += 256) ((float*)psum)[i] = 0.f;
        if (t < 128) gloc[t] = (bm + t < M) ? (batch[bm + t] - g0) : 0;
        // first K-loop __syncthreads() covers these before any use
    }

    for (int kk = 0; kk < K; kk += 32) {
#pragma unroll
        for (int h = 0; h < 128; h += 64) {
            int row = bm + r + h;
            int4 v = make_int4(0, 0, 0, 0);
            if (row < M) v = *(const int4*)&A[(size_t)row * K + kk + kq];
            *(int4*)&As[(r + h) * 40 + kq] = v;
        }
#pragma unroll
        for (int h = 0; h < 128; h += 64) {
            int nrow = bn + r + h;
            int4 v = *(const int4*)&Wt[(size_t)nrow * K + kk + kq];
            *(int4*)&Bs[(r + h) * 40 + kq] = v;
        }
        __syncthreads();
        bf16x8 af[4], bfr[4];
#pragma unroll
        for (int mf = 0; mf < 4; ++mf)
            af[mf] = *(const bf16x8*)&As[(wr * 64 + mf * 16 + lr) * 40 + ko];
#pragma unroll
        for (int nf = 0; nf < 4; ++nf)
            bfr[nf] = *(const bf16x8*)&Bs[(wc * 64 + nf * 16 + lr) * 40 + ko];
#pragma unroll
        for (int mf = 0; mf < 4; ++mf)
#pragma unroll
            for (int nf = 0; nf < 4; ++nf)
                acc[mf][nf] = __builtin_amdgcn_mfma_f32_16x16x32_bf16(af[mf], bfr[nf], acc[mf][nf], 0, 0, 0);
        __syncthreads();
    }

    if (MODE == 1) {
        unsigned char* out8 = (unsigned char*)outp;
#pragma unroll
        for (int mf = 0; mf < 4; ++mf) {
#pragma unroll
            for (int b = 0; b < 4; ++b) {
                int row = bm + wr * 64 + mf * 16 + (lane >> 4) * 4 + b;
                if (row >= M) continue;
                float dv = dinv[row];
#pragma unroll
                for (int nf = 0; nf < 4; ++nf) {
                    int col = bn + wc * 64 + nf * 16 + lr;
                    float v = fmaxf(acc[mf][nf][b] + bias[col], 0.f);
                    out8[(size_t)row * HID + col] = f32_to_fp8(dv * v);
                }
            }
        }
    } else {
        const int q4 = (lane >> 4) << 2;
#pragma unroll
        for (int nf = 0; nf < 4; ++nf) {
            const int lcol = wc * 64 + nf * 16 + lr;
            const float bb = bias[bn + lcol];
            float run = 0.f; int gcur = 0;
#pragma unroll
            for (int mf = 0; mf < 4; ++mf) {
#pragma unroll
                for (int b = 0; b < 4; ++b) {
                    int lrow = wr * 64 + mf * 16 + q4 + b;
                    if (bm + lrow < M) {
                        int gl = gloc[lrow];
                        float v = fmaxf(acc[mf][nf][b] + bb, 0.f);
                        if (gl != gcur) {
                            if (run != 0.f) {
                                if (gcur < 4) atomicAdd(&psum[gcur][lcol], run);
                                else atomicAdd(&pooled[(size_t)(g0 + gcur) * HID + bn + lcol], run);
                            }
                            run = 0.f; gcur = gl;
                        }
                        run += v;
                    }
                }
            }
            if (run != 0.f) {
                if (gcur < 4) atomicAdd(&psum[gcur][lcol], run);
                else atomicAdd(&pooled[(size_t)(g0 + gcur) * HID + bn + lcol], run);
            }
        }
        __syncthreads();
        for (int i = t; i < 4 * 128; i += 256) {
            int gl = i >> 7, lcol = i & 127;
            int g = g0 + gl;
            float v = psum[gl][lcol];
            if (g < NG && v != 0.f)
                atomicAdd(&pooled[(size_t)g * HID + bn + lcol], v);
        }
    }
}

// ---------------- aggregation, 256 channels, fp8 gather, 8-deep MLP ----------------
// out_bf16[d] = bf16(dinv[d] * (hs[d] + sum_{s in N(d)} hs[s])), hs in e4m3

__global__ __launch_bounds__(256) void k_agg256(const unsigned char* __restrict__ hs,
                                                const int* __restrict__ csr,
                                                const int* __restrict__ offs,
                                                const int* __restrict__ deg,
                                                const float* __restrict__ dinv,
                                                unsigned short* __restrict__ out, int n) {
    int wid = threadIdx.x >> 6, lane = threadIdx.x & 63;
    int node = blockIdx.x * 4 + wid;
    if (node >= n) return;
    int c = lane << 2;
    float a0, a1, a2, a3;
    {
        unsigned u = *(const unsigned*)&hs[(size_t)node * HID + c];
        float f[4]; fp8x4_to_f32(u, f);
        a0 = f[0]; a1 = f[1]; a2 = f[2]; a3 = f[3];
    }
    int s0 = offs[node], cnt = deg[node];
    for (int base = 0; base < cnt; base += 64) {
        int nb = min(64, cnt - base);
        int idx = (lane < nb) ? __builtin_nontemporal_load(&csr[s0 + base + lane]) : 0;
        int i = 0;
        for (; i + 8 <= nb; i += 8) {
            unsigned v[8];
#pragma unroll
            for (int k = 0; k < 8; ++k) {
                int j = __shfl(idx, i + k);
                v[k] = *(const unsigned*)&hs[(size_t)j * HID + c];
            }
#pragma unroll
            for (int k = 0; k < 8; ++k) {
                float f[4]; fp8x4_to_f32(v[k], f);
                a0 += f[0]; a1 += f[1]; a2 += f[2]; a3 += f[3];
            }
        }
        for (; i + 4 <= nb; i += 4) {
            unsigned v[4];
#pragma unroll
            for (int k = 0; k < 4; ++k) {
                int j = __shfl(idx, i + k);
                v[k] = *(const unsigned*)&hs[(size_t)j * HID + c];
            }
#pragma unroll
            for (int k = 0; k < 4; ++k) {
                float f[4]; fp8x4_to_f32(v[k], f);
                a0 += f[0]; a1 += f[1]; a2 += f[2]; a3 += f[3];
            }
        }
        for (; i < nb; ++i) {
            int j = __shfl(idx, i);
            unsigned u = *(const unsigned*)&hs[(size_t)j * HID + c];
            float f[4]; fp8x4_to_f32(u, f);
            a0 += f[0]; a1 += f[1]; a2 += f[2]; a3 += f[3];
        }
    }
    float dv = dinv[node];
    ushort4 r;
    r.x = f2bf(dv * a0); r.y = f2bf(dv * a1);
    r.z = f2bf(dv * a2); r.w = f2bf(dv * a3);
    *(ushort4*)&out[(size_t)node * HID + c] = r;
}

// ---------------- aggregation, 128 channels (bf16), 8-deep (4 per 32-lane half) ----------------

__global__ __launch_bounds__(256) void k_agg128(const unsigned short* __restrict__ xs,
                                                const int* __restrict__ csr,
                                                const int* __restrict__ offs,
                                                const int* __restrict__ deg,
                                                const float* __restrict__ dinv,
                                                unsigned short* __restrict__ out, int n) {
    int wid = threadIdx.x >> 6, lane = threadIdx.x & 63;
    int node = blockIdx.x * 4 + wid;
    if (node >= n) return;
    int half = lane >> 5, l32 = lane & 31;
    int c = l32 << 2;
    float a0 = 0.f, a1 = 0.f, a2 = 0.f, a3 = 0.f;
    if (half == 0) {
        const ushort4 s = *(const ushort4*)&xs[(size_t)node * DIN + c];
        a0 = bf2f(s.x); a1 = bf2f(s.y); a2 = bf2f(s.z); a3 = bf2f(s.w);
    }
    int s0 = offs[node], cnt = deg[node];
    for (int base = 0; base < cnt; base += 64) {
        int nb = min(64, cnt - base);
        int idx = (lane < nb) ? __builtin_nontemporal_load(&csr[s0 + base + lane]) : 0;
        int i = 0;
        for (; i + 8 <= nb; i += 8) {
            ushort4 v[4];
#pragma unroll
            for (int k = 0; k < 4; ++k) {
                int j = __shfl(idx, i + 2 * k + half);
                v[k] = *(const ushort4*)&xs[(size_t)j * DIN + c];
            }
#pragma unroll
            for (int k = 0; k < 4; ++k) {
                a0 += bf2f(v[k].x); a1 += bf2f(v[k].y);
                a2 += bf2f(v[k].z); a3 += bf2f(v[k].w);
            }
        }
        for (; i < nb; i += 2) {
            int e = i + half;
            int j = __shfl(idx, e < nb ? e : 0);
            if (e < nb) {
                const ushort4 v = *(const ushort4*)&xs[(size_t)j * DIN + c];
                a0 += bf2f(v.x); a1 += bf2f(v.y); a2 += bf2f(v.z); a3 += bf2f(v.w);
            }
        }
    }
    a0 += __shfl_xor(a0, 32);
    a1 += __shfl_xor(a1, 32);
    a2 += __shfl_xor(a2, 32);
    a3 += __shfl_xor(a3, 32);
    if (half == 0) {
        float dv = dinv[node];
        ushort4 r;
        r.x = f2bf(dv * a0); r.y = f2bf(dv * a1);
        r.z = f2bf(dv * a2); r.w = f2bf(dv * a3);
        *(ushort4*)&out[(size_t)node * DIN + c] = r;
    }
}

// ---------------- head MLP ----------------

__global__ __launch_bounds__(256) void k_mlp(const float* __restrict__ pooled,
                                             const float* __restrict__ countsf,
                                             const float* __restrict__ Wf1,
                                             const float* __restrict__ bf1,
                                             const float* __restrict__ Wf2,
                                             const float* __restrict__ bf2,
                                             float* __restrict__ out) {
    __shared__ float p[HID];
    __shared__ float z[HID];
    int g = blockIdx.x, t = threadIdx.x;
    float cnt = fmaxf(countsf[g], 1.0f);
    p[t] = pooled[g * HID + t] / cnt;
    __syncthreads();
    float accz = bf1[t];
    for (int k = 0; k < HID; ++k)
        accz = fmaf(p[k], Wf1[k * HID + t], accz);
    z[t] = fmaxf(accz, 0.f);
    __syncthreads();
    if (t < NCLS) {
        float o = bf2[t];
        for (int k = 0; k < HID; ++k)
            o = fmaf(z[k], Wf2[k * NCLS + t], o);
        float sp = fmaxf(o, 0.f) + log1pf(expf(-fabsf(o)));
        out[g * NCLS + t] = sp + 0.001f;
    }
}

// ---------------- launch ----------------

extern "C" void kernel_launch(void* const* d_in, const int* in_sizes, int n_in,
                              void* d_out, int out_size, void* d_ws, size_t ws_size,
                              hipStream_t stream) {
    const float* x     = (const float*)d_in[0];
    const int*   ei    = (const int*)d_in[1];
    const int*   batch = (const int*)d_in[2];
    const float* W1    = (const float*)d_in[3];
    const float* b1    = (const float*)d_in[4];
    const float* W2    = (const float*)d_in[5];
    const float* b2    = (const float*)d_in[6];
    const float* Wf1   = (const float*)d_in[7];
    const float* bf1   = (const float*)d_in[8];
    const float* Wf2   = (const float*)d_in[9];
    const float* bf2   = (const float*)d_in[10];
    float* out = (float*)d_out;

    const int* srcv = ei;
    const int* dstv = ei + NE;

    char* p = (char*)d_ws;
    auto take = [&](size_t bytes) -> char* {
        char* q = p; p += (bytes + 255) & ~(size_t)255; return q;
    };
    unsigned short* big0 = (unsigned short*)take((size_t)NN * HID * 2);
    unsigned short* big1 = (unsigned short*)take((size_t)NN * HID * 2);
    unsigned short* xs = big0;
    unsigned short* xa = big0 + (size_t)NN * DIN;
    unsigned char*  h8 = (unsigned char*)big1;   // layer-1 output, fp8 e4m3 (25.6 MB)
    unsigned short* rB = big0;                   // aggregated layer-2 input, bf16
    int2* pairs = (int2*)big1;                   // alias: dead before h8 written
    unsigned short* wt1  = (unsigned short*)take((size_t)DIN * HID * 2);
    unsigned short* wt2  = (unsigned short*)take((size_t)HID * HID * 2);
    int*   histg   = (int*)take((size_t)NBUK * NBLK * 4);
    int*   deg     = (int*)take((size_t)NN * 4);
    int*   offs    = (int*)take((size_t)NN * 4);
    int*   csr     = (int*)take((size_t)NE * 4);
    float* dinv    = (float*)take((size_t)NN * 4);
    float* pooled  = (float*)take((size_t)NG * HID * 4);
    float* countsf = (float*)take((size_t)NG * 4);

    hipMemsetAsync(pooled, 0, (size_t)NG * HID * 4, stream);

    k_hist<<<NBLK, 256, 0, stream>>>(dstv, histg);
    k_scan64k<<<1, 1024, 0, stream>>>(histg);
    k_scatter<<<NBLK, 256, 0, stream>>>(srcv, dstv, histg, pairs);
    k_csr<<<NBUK, 256, 0, stream>>>(pairs, histg, csr, deg, dinv, offs);
    k_counts<<<1, 64, 0, stream>>>(batch, countsf);

    k_cast_scale_x<<<(NN * DIN / 4 + 255) / 256, 256, 0, stream>>>(x, dinv, xs, NN * DIN / 4);
    k_cast_wt2<<<((DIN + HID) * HID + 255) / 256, 256, 0, stream>>>(W1, wt1, W2, wt2);

    dim3 gg((NN + 127) / 128, HID / 128);
    // layer 1 (epilogue writes fp8)
    k_agg128<<<(NN + 3) / 4, 256, 0, stream>>>(xs, csr, offs, deg, dinv, xa, NN);
    k_gemm_mfma<1><<<gg, 256, 0, stream>>>(xa, wt1, dinv, b1, (void*)h8, batch, pooled, NN, DIN);
    // layer 2: fp8 gather, then GEMM2 (+ fused pooling)
    k_agg256<<<(NN + 3) / 4, 256, 0, stream>>>(h8, csr, offs, deg, dinv, rB, NN);
    k_gemm_mfma<2><<<gg, 256, 0, stream>>>(rB, wt2, dinv, b2, nullptr, batch, pooled, NN, HID);

    k_mlp<<<NG, 256, 0, stream>>>(pooled, countsf, Wf1, bf1, Wf2, bf2, out);
}